// Round 2
// baseline (2915.944 us; speedup 1.0000x reference)
//
#include <hip/hip_runtime.h>
#include <hip/hip_bf16.h>
#include <math.h>

// Problem constants (match reference)
#define BATCH 2
#define HH 112
#define WW 112
#define CC 128
#define NHEADS 4
#define HD 32
#define RAD 2
#define WS1 5
#define WSZ 25
#define M_TOT (BATCH * HH * WW)   // 25088 = 392 * 64 = 196 * 128

// ---------------------------------------------------------------------------
// Tiled fp32 GEMM with bias: C[m][n] = sum_k A[m][k] * B[k][n] + bias[n]
// 256 threads; micro-tile TM x TN per thread; K compile-time (full unroll).
// As transposed with +4 pad: rows stay 16B-aligned -> ds_read_b128 fragments.
// ---------------------------------------------------------------------------
template <int BM, int BN, int BK, int TM, int TN, int K>
__global__ __launch_bounds__(256)
void gemm_bias_kernel(const float* __restrict__ A, const float* __restrict__ Bw,
                      const float* __restrict__ bias, float* __restrict__ Cout,
                      int M, int N) {
    __shared__ float As[BK][BM + 4];  // transposed; +4 keeps rows 16B-aligned
    __shared__ float Bs[BK][BN];      // natural orientation

    constexpr int TCOLS = BN / TN;    // threads along n
    static_assert((BM / TM) * (BN / TN) == 256, "256 threads");

    const int tid = threadIdx.x;
    const int tn = tid % TCOLS;
    const int tm = tid / TCOLS;
    const int m0 = blockIdx.x * BM;
    const int n0 = blockIdx.y * BN;

    float acc[TM][TN] = {};

    constexpr int A_F4 = BM * BK / 4; // float4s per A tile
    constexpr int B_F4 = BK * BN / 4;

#pragma unroll
    for (int k0 = 0; k0 < K; k0 += BK) {
        // --- stage A tile (transpose into LDS) ---
#pragma unroll
        for (int f = tid; f < A_F4; f += 256) {
            int r = f / (BK / 4);         // A row within tile
            int c4 = f % (BK / 4);        // float4 along K
            float4 v = *reinterpret_cast<const float4*>(
                &A[(size_t)(m0 + r) * K + k0 + c4 * 4]);
            As[c4 * 4 + 0][r] = v.x;
            As[c4 * 4 + 1][r] = v.y;
            As[c4 * 4 + 2][r] = v.z;
            As[c4 * 4 + 3][r] = v.w;
        }
        // --- stage B tile (natural) ---
#pragma unroll
        for (int f = tid; f < B_F4; f += 256) {
            int r = f / (BN / 4);
            int c4 = f % (BN / 4);
            *reinterpret_cast<float4*>(&Bs[r][c4 * 4]) =
                *reinterpret_cast<const float4*>(
                    &Bw[(size_t)(k0 + r) * N + n0 + c4 * 4]);
        }
        __syncthreads();

#pragma unroll
        for (int k = 0; k < BK; ++k) {
            float a[TM], b[TN];
#pragma unroll
            for (int i = 0; i < TM; i += 4) {
                float4 v = *reinterpret_cast<const float4*>(&As[k][tm * TM + i]);
                a[i] = v.x; a[i + 1] = v.y; a[i + 2] = v.z; a[i + 3] = v.w;
            }
#pragma unroll
            for (int j = 0; j < TN; j += 4) {
                float4 v = *reinterpret_cast<const float4*>(&Bs[k][tn * TN + j]);
                b[j] = v.x; b[j + 1] = v.y; b[j + 2] = v.z; b[j + 3] = v.w;
            }
#pragma unroll
            for (int i = 0; i < TM; ++i)
#pragma unroll
                for (int j = 0; j < TN; ++j) acc[i][j] += a[i] * b[j];
        }
        __syncthreads();
    }

    // --- epilogue: bias + float4 stores ---
#pragma unroll
    for (int i = 0; i < TM; ++i) {
        int m = m0 + tm * TM + i;
#pragma unroll
        for (int j = 0; j < TN; j += 4) {
            int n = n0 + tn * TN + j;
            float4 o;
            o.x = acc[i][j + 0] + bias[n + 0];
            o.y = acc[i][j + 1] + bias[n + 1];
            o.z = acc[i][j + 2] + bias[n + 2];
            o.w = acc[i][j + 3] + bias[n + 3];
            *reinterpret_cast<float4*>(&Cout[(size_t)m * N + n]) = o;
        }
    }
}

// ---------------------------------------------------------------------------
// Windowed attention: one wave (64 lanes) per pixel, 4 pixels per 256-block.
// Lane owns channels (2*lane, 2*lane+1); head = lane>>4 (16 lanes / head).
// Reflect indexing on the fly; scores in fully-unrolled register arrays.
// qkv layout per pixel: [0:128)=Q, [128:256)=K, [256:384)=V.
// ---------------------------------------------------------------------------
__global__ __launch_bounds__(256)
void attn_kernel(const float* __restrict__ qkv, float* __restrict__ attn_out) {
    const int lane = threadIdx.x & 63;
    const int wv = threadIdx.x >> 6;
    const int pix = blockIdx.x * 4 + wv;

    const int bw = pix / (HH * WW);
    const int rem = pix - bw * (HH * WW);
    const int y = rem / WW;
    const int x = rem - y * WW;
    const int c0 = lane * 2;
    const float scale = 0.1767766952966369f;  // 1/sqrt(32)

    const float2 q = *reinterpret_cast<const float2*>(&qkv[(size_t)pix * 384 + c0]);

    float s[WSZ];
    int np[WSZ];

#pragma unroll
    for (int dy = 0; dy < WS1; ++dy) {
        int yy = y + dy - RAD;
        yy = yy < 0 ? -yy : (yy >= HH ? 2 * (HH - 1) - yy : yy);
#pragma unroll
        for (int dx = 0; dx < WS1; ++dx) {
            int xx = x + dx - RAD;
            xx = xx < 0 ? -xx : (xx >= WW ? 2 * (WW - 1) - xx : xx);
            const int wi = dy * WS1 + dx;
            const int n = (bw * HH + yy) * WW + xx;
            np[wi] = n;
            const float2 kv =
                *reinterpret_cast<const float2*>(&qkv[(size_t)n * 384 + 128 + c0]);
            float partial = q.x * kv.x + q.y * kv.y;
            // butterfly reduce across the 16 lanes of this head (wave = 64!)
            partial += __shfl_xor(partial, 1);
            partial += __shfl_xor(partial, 2);
            partial += __shfl_xor(partial, 4);
            partial += __shfl_xor(partial, 8);
            s[wi] = partial * scale;
        }
    }

    // softmax over 25 window positions (redundant across the 16 head lanes)
    float mx = s[0];
#pragma unroll
    for (int i = 1; i < WSZ; ++i) mx = fmaxf(mx, s[i]);
    float sum = 0.f;
#pragma unroll
    for (int i = 0; i < WSZ; ++i) {
        s[i] = __expf(s[i] - mx);
        sum += s[i];
    }
    const float inv = 1.0f / sum;

    float o0 = 0.f, o1 = 0.f;
#pragma unroll
    for (int i = 0; i < WSZ; ++i) {
        const float2 vv =
            *reinterpret_cast<const float2*>(&qkv[(size_t)np[i] * 384 + 256 + c0]);
        const float p = s[i] * inv;
        o0 += p * vv.x;
        o1 += p * vv.y;
    }

    *reinterpret_cast<float2*>(&attn_out[(size_t)pix * 128 + c0]) =
        make_float2(o0, o1);
}

// ---------------------------------------------------------------------------
extern "C" void kernel_launch(void* const* d_in, const int* in_sizes, int n_in,
                              void* d_out, int out_size, void* d_ws, size_t ws_size,
                              hipStream_t stream) {
    const float* x = (const float*)d_in[0];       // [B,H,W,C]
    const float* w_qkv = (const float*)d_in[1];   // [C, 3C] row-major (in,out)
    const float* b_qkv = (const float*)d_in[2];   // [3C]
    const float* w_out = (const float*)d_in[3];   // [C, C]
    const float* b_out = (const float*)d_in[4];   // [C]
    float* out = (float*)d_out;

    float* qkv = (float*)d_ws;                              // 25088*384 floats
    float* attn_out = qkv + (size_t)M_TOT * 3 * CC;         // 25088*128 floats

    // Kernel A: qkv = x @ w_qkv + b_qkv   (M=25088, N=384, K=128)
    {
        dim3 grid(M_TOT / 128, (3 * CC) / 128);   // 196 x 3
        gemm_bias_kernel<128, 128, 32, 8, 8, CC><<<grid, 256, 0, stream>>>(
            x, w_qkv, b_qkv, qkv, M_TOT, 3 * CC);
    }

    // Kernel B: windowed attention (one wave per pixel)
    {
        dim3 grid(M_TOT / 4);
        attn_kernel<<<grid, 256, 0, stream>>>(qkv, attn_out);
    }

    // Kernel C: out = attn_out @ w_out + b_out   (M=25088, N=128, K=128)
    {
        dim3 grid(M_TOT / 64, CC / 64);           // 392 x 2
        gemm_bias_kernel<64, 64, 32, 4, 4, CC><<<grid, 256, 0, stream>>>(
            attn_out, w_out, b_out, out, M_TOT, CC);
    }
}

// Round 5
// 175.332 us; speedup vs baseline: 16.6310x; 16.6310x over previous
//
#include <hip/hip_runtime.h>
#include <hip/hip_bf16.h>
#include <math.h>

// Problem constants (match reference)
#define BATCH 2
#define HH 112
#define WW 112
#define CC 128
#define NHEADS 4
#define HD 32
#define RAD 2
#define WS1 5
#define WSZ 25
#define M_TOT (BATCH * HH * WW)   // 25088 = 392 * 64 = 196 * 128

// ---------------------------------------------------------------------------
// Tiled fp32 GEMM with bias: C[m][n] = sum_k A[m][k] * B[k][n] + bias[n]
// 256 threads; micro-tile TM x TN per thread; K compile-time.
// NOTE: outer k0 loop is intentionally NOT unrolled (#pragma unroll 1):
// round-2 full unroll spilled (VGPR=256, 4 GB scratch traffic, 2215 us).
// ---------------------------------------------------------------------------
template <int BM, int BN, int BK, int TM, int TN, int K>
__global__ __launch_bounds__(256)
void gemm_bias_kernel(const float* __restrict__ A, const float* __restrict__ Bw,
                      const float* __restrict__ bias, float* __restrict__ Cout,
                      int M, int N) {
    __shared__ float As[BK][BM + 4];  // transposed; +4 keeps rows 16B-aligned
    __shared__ float Bs[BK][BN];      // natural orientation

    constexpr int TCOLS = BN / TN;    // threads along n
    static_assert((BM / TM) * (BN / TN) == 256, "256 threads");

    const int tid = threadIdx.x;
    const int tn = tid % TCOLS;
    const int tm = tid / TCOLS;
    const int m0 = blockIdx.x * BM;
    const int n0 = blockIdx.y * BN;

    constexpr int A_F4 = BM * BK / 4; // float4s per A tile
    constexpr int B_F4 = BK * BN / 4;

    // thread-constant staging coordinates (hoisted)
    const int ar0 = tid / (BK / 4);         // A row within tile (first chunk)
    const int ac4 = tid % (BK / 4);         // A float4 along K
    const int br0 = tid / (BN / 4);         // B row within tile
    const int bc4 = tid % (BN / 4);

    float acc[TM][TN] = {};

#pragma unroll 1
    for (int k0 = 0; k0 < K; k0 += BK) {
        // --- stage A tile (transpose into LDS) ---
#pragma unroll
        for (int l = 0; l < A_F4 / 256; ++l) {
            int r = ar0 + l * (256 / (BK / 4));
            float4 v = *reinterpret_cast<const float4*>(
                &A[(size_t)(m0 + r) * K + k0 + ac4 * 4]);
            As[ac4 * 4 + 0][r] = v.x;
            As[ac4 * 4 + 1][r] = v.y;
            As[ac4 * 4 + 2][r] = v.z;
            As[ac4 * 4 + 3][r] = v.w;
        }
        // --- stage B tile (natural) ---
#pragma unroll
        for (int l = 0; l < B_F4 / 256; ++l) {
            int r = br0 + l * (256 / (BN / 4));
            *reinterpret_cast<float4*>(&Bs[r][bc4 * 4]) =
                *reinterpret_cast<const float4*>(
                    &Bw[(size_t)(k0 + r) * N + n0 + bc4 * 4]);
        }
        __syncthreads();

#pragma unroll
        for (int k = 0; k < BK; ++k) {
            float a[TM], b[TN];
#pragma unroll
            for (int i = 0; i < TM; i += 4) {
                float4 v = *reinterpret_cast<const float4*>(&As[k][tm * TM + i]);
                a[i] = v.x; a[i + 1] = v.y; a[i + 2] = v.z; a[i + 3] = v.w;
            }
#pragma unroll
            for (int j = 0; j < TN; j += 4) {
                float4 v = *reinterpret_cast<const float4*>(&Bs[k][tn * TN + j]);
                b[j] = v.x; b[j + 1] = v.y; b[j + 2] = v.z; b[j + 3] = v.w;
            }
#pragma unroll
            for (int i = 0; i < TM; ++i)
#pragma unroll
                for (int j = 0; j < TN; ++j) acc[i][j] += a[i] * b[j];
        }
        __syncthreads();
    }

    // --- epilogue: bias + float4 stores ---
#pragma unroll
    for (int i = 0; i < TM; ++i) {
        int m = m0 + tm * TM + i;
#pragma unroll
        for (int j = 0; j < TN; j += 4) {
            int n = n0 + tn * TN + j;
            float4 o;
            o.x = acc[i][j + 0] + bias[n + 0];
            o.y = acc[i][j + 1] + bias[n + 1];
            o.z = acc[i][j + 2] + bias[n + 2];
            o.w = acc[i][j + 3] + bias[n + 3];
            *reinterpret_cast<float4*>(&Cout[(size_t)m * N + n]) = o;
        }
    }
}

// ---------------------------------------------------------------------------
// Windowed attention: one wave (64 lanes) per pixel, 4 pixels per 256-block.
// Lane owns channels (2*lane, 2*lane+1); head = lane>>4 (16 lanes / head).
// Reflect indexing on the fly; scores in fully-unrolled register arrays.
// qkv layout per pixel: [0:128)=Q, [128:256)=K, [256:384)=V.
// ---------------------------------------------------------------------------
__global__ __launch_bounds__(256)
void attn_kernel(const float* __restrict__ qkv, float* __restrict__ attn_out) {
    const int lane = threadIdx.x & 63;
    const int wv = threadIdx.x >> 6;
    const int pix = blockIdx.x * 4 + wv;

    const int bw = pix / (HH * WW);
    const int rem = pix - bw * (HH * WW);
    const int y = rem / WW;
    const int x = rem - y * WW;
    const int c0 = lane * 2;
    const float scale = 0.1767766952966369f;  // 1/sqrt(32)

    const float2 q = *reinterpret_cast<const float2*>(&qkv[(size_t)pix * 384 + c0]);

    float s[WSZ];
    int np[WSZ];

#pragma unroll
    for (int dy = 0; dy < WS1; ++dy) {
        int yy = y + dy - RAD;
        yy = yy < 0 ? -yy : (yy >= HH ? 2 * (HH - 1) - yy : yy);
#pragma unroll
        for (int dx = 0; dx < WS1; ++dx) {
            int xx = x + dx - RAD;
            xx = xx < 0 ? -xx : (xx >= WW ? 2 * (WW - 1) - xx : xx);
            const int wi = dy * WS1 + dx;
            const int n = (bw * HH + yy) * WW + xx;
            np[wi] = n;
            const float2 kv =
                *reinterpret_cast<const float2*>(&qkv[(size_t)n * 384 + 128 + c0]);
            float partial = q.x * kv.x + q.y * kv.y;
            // butterfly reduce across the 16 lanes of this head (wave = 64!)
            partial += __shfl_xor(partial, 1);
            partial += __shfl_xor(partial, 2);
            partial += __shfl_xor(partial, 4);
            partial += __shfl_xor(partial, 8);
            s[wi] = partial * scale;
        }
    }

    // softmax over 25 window positions (redundant across the 16 head lanes)
    float mx = s[0];
#pragma unroll
    for (int i = 1; i < WSZ; ++i) mx = fmaxf(mx, s[i]);
    float sum = 0.f;
#pragma unroll
    for (int i = 0; i < WSZ; ++i) {
        s[i] = __expf(s[i] - mx);
        sum += s[i];
    }
    const float inv = 1.0f / sum;

    float o0 = 0.f, o1 = 0.f;
#pragma unroll
    for (int i = 0; i < WSZ; ++i) {
        const float2 vv =
            *reinterpret_cast<const float2*>(&qkv[(size_t)np[i] * 384 + 256 + c0]);
        const float p = s[i] * inv;
        o0 += p * vv.x;
        o1 += p * vv.y;
    }

    *reinterpret_cast<float2*>(&attn_out[(size_t)pix * 128 + c0]) =
        make_float2(o0, o1);
}

// ---------------------------------------------------------------------------
extern "C" void kernel_launch(void* const* d_in, const int* in_sizes, int n_in,
                              void* d_out, int out_size, void* d_ws, size_t ws_size,
                              hipStream_t stream) {
    const float* x = (const float*)d_in[0];       // [B,H,W,C]
    const float* w_qkv = (const float*)d_in[1];   // [C, 3C] row-major (in,out)
    const float* b_qkv = (const float*)d_in[2];   // [3C]
    const float* w_out = (const float*)d_in[3];   // [C, C]
    const float* b_out = (const float*)d_in[4];   // [C]
    float* out = (float*)d_out;

    float* qkv = (float*)d_ws;                              // 25088*384 floats
    float* attn_out = qkv + (size_t)M_TOT * 3 * CC;         // 25088*128 floats

    // Kernel A: qkv = x @ w_qkv + b_qkv   (M=25088, N=384, K=128)
    {
        dim3 grid(M_TOT / 128, (3 * CC) / 128);   // 196 x 3
        gemm_bias_kernel<128, 128, 32, 8, 8, CC><<<grid, 256, 0, stream>>>(
            x, w_qkv, b_qkv, qkv, M_TOT, 3 * CC);
    }

    // Kernel B: windowed attention (one wave per pixel)
    {
        dim3 grid(M_TOT / 4);
        attn_kernel<<<grid, 256, 0, stream>>>(qkv, attn_out);
    }

    // Kernel C: out = attn_out @ w_out + b_out   (M=25088, N=128, K=128)
    {
        dim3 grid(M_TOT / 64, CC / 64);           // 392 x 2
        gemm_bias_kernel<64, 64, 32, 4, 4, CC><<<grid, 256, 0, stream>>>(
            attn_out, w_out, b_out, out, M_TOT, CC);
    }
}

// Round 14
// 161.680 us; speedup vs baseline: 18.0353x; 1.0844x over previous
//
#include <hip/hip_runtime.h>
#include <hip/hip_bf16.h>
#include <math.h>

// Problem constants (match reference)
#define BATCH 2
#define HH 112
#define WW 112
#define CC 128
#define NHEADS 4
#define HD 32
#define RAD 2
#define WS1 5
#define WSZ 25
#define M_TOT (BATCH * HH * WW)   // 25088 = 392 * 64 = 196 * 128 = 1568 * 16

// ---------------------------------------------------------------------------
// Tiled fp32 GEMM with bias: C[m][n] = sum_k A[m][k] * B[k][n] + bias[n]
// 256 threads; micro-tile TM x TN per thread; K compile-time.
// NOTE: outer k0 loop intentionally NOT unrolled (#pragma unroll 1):
// round-2 full unroll spilled (VGPR=256, 4 GB scratch traffic, 2215 us).
// ---------------------------------------------------------------------------
template <int BM, int BN, int BK, int TM, int TN, int K>
__global__ __launch_bounds__(256)
void gemm_bias_kernel(const float* __restrict__ A, const float* __restrict__ Bw,
                      const float* __restrict__ bias, float* __restrict__ Cout,
                      int M, int N) {
    __shared__ float As[BK][BM + 4];  // transposed; +4 keeps rows 16B-aligned
    __shared__ float Bs[BK][BN];      // natural orientation

    constexpr int TCOLS = BN / TN;    // threads along n
    static_assert((BM / TM) * (BN / TN) == 256, "256 threads");

    const int tid = threadIdx.x;
    const int tn = tid % TCOLS;
    const int tm = tid / TCOLS;
    const int m0 = blockIdx.x * BM;
    const int n0 = blockIdx.y * BN;

    constexpr int A_F4 = BM * BK / 4; // float4s per A tile
    constexpr int B_F4 = BK * BN / 4;

    // thread-constant staging coordinates (hoisted)
    const int ar0 = tid / (BK / 4);         // A row within tile (first chunk)
    const int ac4 = tid % (BK / 4);         // A float4 along K
    const int br0 = tid / (BN / 4);         // B row within tile
    const int bc4 = tid % (BN / 4);

    float acc[TM][TN] = {};

#pragma unroll 1
    for (int k0 = 0; k0 < K; k0 += BK) {
        // --- stage A tile (transpose into LDS) ---
#pragma unroll
        for (int l = 0; l < A_F4 / 256; ++l) {
            int r = ar0 + l * (256 / (BK / 4));
            float4 v = *reinterpret_cast<const float4*>(
                &A[(size_t)(m0 + r) * K + k0 + ac4 * 4]);
            As[ac4 * 4 + 0][r] = v.x;
            As[ac4 * 4 + 1][r] = v.y;
            As[ac4 * 4 + 2][r] = v.z;
            As[ac4 * 4 + 3][r] = v.w;
        }
        // --- stage B tile (natural) ---
#pragma unroll
        for (int l = 0; l < B_F4 / 256; ++l) {
            int r = br0 + l * (256 / (BN / 4));
            *reinterpret_cast<float4*>(&Bs[r][bc4 * 4]) =
                *reinterpret_cast<const float4*>(
                    &Bw[(size_t)(k0 + r) * N + n0 + bc4 * 4]);
        }
        __syncthreads();

#pragma unroll
        for (int k = 0; k < BK; ++k) {
            float a[TM], b[TN];
#pragma unroll
            for (int i = 0; i < TM; i += 4) {
                float4 v = *reinterpret_cast<const float4*>(&As[k][tm * TM + i]);
                a[i] = v.x; a[i + 1] = v.y; a[i + 2] = v.z; a[i + 3] = v.w;
            }
#pragma unroll
            for (int j = 0; j < TN; j += 4) {
                float4 v = *reinterpret_cast<const float4*>(&Bs[k][tn * TN + j]);
                b[j] = v.x; b[j + 1] = v.y; b[j + 2] = v.z; b[j + 3] = v.w;
            }
#pragma unroll
            for (int i = 0; i < TM; ++i)
#pragma unroll
                for (int j = 0; j < TN; ++j) acc[i][j] += a[i] * b[j];
        }
        __syncthreads();
    }

    // --- epilogue: bias + float4 stores ---
#pragma unroll
    for (int i = 0; i < TM; ++i) {
        int m = m0 + tm * TM + i;
#pragma unroll
        for (int j = 0; j < TN; j += 4) {
            int n = n0 + tn * TN + j;
            float4 o;
            o.x = acc[i][j + 0] + bias[n + 0];
            o.y = acc[i][j + 1] + bias[n + 1];
            o.z = acc[i][j + 2] + bias[n + 2];
            o.w = acc[i][j + 3] + bias[n + 3];
            *reinterpret_cast<float4*>(&Cout[(size_t)m * N + n]) = o;
        }
    }
}

// ---------------------------------------------------------------------------
// Windowed attention v2: 4 pixels per wave (16 lanes each), 16 pixels/block.
// Lane owns 8 channels: sub = tid&15, c0 = sub*8 -> two float4 loads per
// position. Head = sub>>2 (4 lanes per head) -> dot reduce = 2 shuffles.
// vs v1 (1 pixel/wave, 2ch/lane, 4-deep shuffle): ~4x fewer wave-insts/pixel.
// qkv layout per pixel: [0:128)=Q, [128:256)=K, [256:384)=V.
// ---------------------------------------------------------------------------
__global__ __launch_bounds__(256)
void attn_kernel(const float* __restrict__ qkv, float* __restrict__ attn_out) {
    const int tid = threadIdx.x;
    const int sub = tid & 15;                 // slot within pixel
    const int pix = blockIdx.x * 16 + (tid >> 4);
    const int c0 = sub * 8;                   // 8 channels per lane (one head's 8)

    const int bw = pix / (HH * WW);
    const int rem = pix - bw * (HH * WW);
    const int y = rem / WW;
    const int x = rem - y * WW;
    const float scale = 0.1767766952966369f;  // 1/sqrt(32)

    const float4 q0 = *reinterpret_cast<const float4*>(&qkv[(size_t)pix * 384 + c0]);
    const float4 q1 = *reinterpret_cast<const float4*>(&qkv[(size_t)pix * 384 + c0 + 4]);

    float s[WSZ];
    int np[WSZ];

#pragma unroll
    for (int dy = 0; dy < WS1; ++dy) {
        int yy = y + dy - RAD;
        yy = yy < 0 ? -yy : (yy >= HH ? 2 * (HH - 1) - yy : yy);
#pragma unroll
        for (int dx = 0; dx < WS1; ++dx) {
            int xx = x + dx - RAD;
            xx = xx < 0 ? -xx : (xx >= WW ? 2 * (WW - 1) - xx : xx);
            const int wi = dy * WS1 + dx;
            const int n = (bw * HH + yy) * WW + xx;
            np[wi] = n;
            const float4 k0 =
                *reinterpret_cast<const float4*>(&qkv[(size_t)n * 384 + 128 + c0]);
            const float4 k1 =
                *reinterpret_cast<const float4*>(&qkv[(size_t)n * 384 + 128 + c0 + 4]);
            float partial = q0.x * k0.x + q0.y * k0.y + q0.z * k0.z + q0.w * k0.w +
                            q1.x * k1.x + q1.y * k1.y + q1.z * k1.z + q1.w * k1.w;
            // reduce across the 4 lanes of this head (xor 1,2 stay in-group)
            partial += __shfl_xor(partial, 1);
            partial += __shfl_xor(partial, 2);
            s[wi] = partial * scale;
        }
    }

    // softmax over 25 window positions (redundant across the 4 head lanes)
    float mx = s[0];
#pragma unroll
    for (int i = 1; i < WSZ; ++i) mx = fmaxf(mx, s[i]);
    float sum = 0.f;
#pragma unroll
    for (int i = 0; i < WSZ; ++i) {
        s[i] = __expf(s[i] - mx);
        sum += s[i];
    }
    const float inv = 1.0f / sum;

    float4 o0 = make_float4(0.f, 0.f, 0.f, 0.f);
    float4 o1 = make_float4(0.f, 0.f, 0.f, 0.f);
#pragma unroll
    for (int i = 0; i < WSZ; ++i) {
        const float4 v0 =
            *reinterpret_cast<const float4*>(&qkv[(size_t)np[i] * 384 + 256 + c0]);
        const float4 v1 =
            *reinterpret_cast<const float4*>(&qkv[(size_t)np[i] * 384 + 256 + c0 + 4]);
        const float p = s[i] * inv;
        o0.x += p * v0.x; o0.y += p * v0.y; o0.z += p * v0.z; o0.w += p * v0.w;
        o1.x += p * v1.x; o1.y += p * v1.y; o1.z += p * v1.z; o1.w += p * v1.w;
    }

    *reinterpret_cast<float4*>(&attn_out[(size_t)pix * 128 + c0]) = o0;
    *reinterpret_cast<float4*>(&attn_out[(size_t)pix * 128 + c0 + 4]) = o1;
}

// ---------------------------------------------------------------------------
extern "C" void kernel_launch(void* const* d_in, const int* in_sizes, int n_in,
                              void* d_out, int out_size, void* d_ws, size_t ws_size,
                              hipStream_t stream) {
    const float* x = (const float*)d_in[0];       // [B,H,W,C]
    const float* w_qkv = (const float*)d_in[1];   // [C, 3C] row-major (in,out)
    const float* b_qkv = (const float*)d_in[2];   // [3C]
    const float* w_out = (const float*)d_in[3];   // [C, C]
    const float* b_out = (const float*)d_in[4];   // [C]
    float* out = (float*)d_out;

    float* qkv = (float*)d_ws;                              // 25088*384 floats
    float* attn_out = qkv + (size_t)M_TOT * 3 * CC;         // 25088*128 floats

    // Kernel A: qkv = x @ w_qkv + b_qkv   (M=25088, N=384, K=128)
    {
        dim3 grid(M_TOT / 128, (3 * CC) / 128);   // 196 x 3
        gemm_bias_kernel<128, 128, 32, 8, 8, CC><<<grid, 256, 0, stream>>>(
            x, w_qkv, b_qkv, qkv, M_TOT, 3 * CC);
    }

    // Kernel B: windowed attention (4 pixels per wave, 16 per block)
    {
        dim3 grid(M_TOT / 16);                    // 1568
        attn_kernel<<<grid, 256, 0, stream>>>(qkv, attn_out);
    }

    // Kernel C: out = attn_out @ w_out + b_out   (M=25088, N=128, K=128)
    // 128x64 tile / 8x4 micro-tile: better FMA:LDS ratio than 64x64/4x4,
    // still 392 blocks for 256 CUs.
    {
        dim3 grid(M_TOT / 128, CC / 64);          // 196 x 2
        gemm_bias_kernel<128, 64, 32, 8, 4, CC><<<grid, 256, 0, stream>>>(
            attn_out, w_out, b_out, out, M_TOT, CC);
    }
}

// Round 15
// 136.170 us; speedup vs baseline: 21.4141x; 1.1873x over previous
//
#include <hip/hip_runtime.h>
#include <hip/hip_bf16.h>
#include <math.h>

// Problem constants (match reference)
#define BATCH 2
#define HH 112
#define WW 112
#define CC 128
#define NHEADS 4
#define RAD 2
#define WS1 5
#define WSZ 25
#define M_TOT (BATCH * HH * WW)   // 25088 = 196 * 128 = 1568 * 16

typedef __attribute__((ext_vector_type(8))) short bf16x8;  // MFMA A/B frag (4 VGPR)
typedef __attribute__((ext_vector_type(4))) float f32x4;   // MFMA C/D frag

// ---- fp32 -> bf16 RNE via bit math (no header-API dependence) ----
__device__ __forceinline__ ushort bf16_rne(float x) {
    unsigned u = __float_as_uint(x);
    unsigned r = u + 0x7FFFu + ((u >> 16) & 1u);
    return (ushort)(r >> 16);
}
__device__ __forceinline__ float bf16_to_f(ushort h) {
    return __uint_as_float(((unsigned)h) << 16);
}

// ---------------------------------------------------------------------------
// Pre-pass: W[K=128][N] fp32 -> transposed bf16 hi/lo planes Wt[N][128].
// Run once per launch (ws is re-poisoned every timed call). Tiny (<2 us).
// ---------------------------------------------------------------------------
__global__ __launch_bounds__(256)
void wsplit_kernel(const float* __restrict__ W, ushort* __restrict__ Wt_hi,
                   ushort* __restrict__ Wt_lo, int N) {
    int idx = blockIdx.x * 256 + threadIdx.x;   // over K*N
    int k = idx / N;
    int n = idx - k * N;
    float x = W[idx];
    ushort h = bf16_rne(x);
    float rem = x - bf16_to_f(h);
    ushort l = bf16_rne(rem);
    Wt_hi[n * CC + k] = h;
    Wt_lo[n * CC + k] = l;
}

// ---------------------------------------------------------------------------
// MFMA GEMM with bias: C[m][n] = sum_k A[m][k]*W[k][n] + bias[n]
// A fp32 [M][128]; W pre-transposed+split bf16 planes Wt[N][128].
// hi/lo split 3-pass (Ah*Bh + Ah*Bl + Al*Bh): ~2^-17 rel err (fp32-class).
// BM=128, BN=64, BK=32, K=128 (4 k-iters). 256 thr = 4 waves; wave w owns
// rows [w*32, w*32+32) = 2 m-tiles x 4 n-tiles of 16x16.
// Frag maps (guide-verified m89/m91): operand row = lane&15, k-octet=lane>>4;
// D: col = lane&15, row = (lane>>4)*4 + reg. k-octet order cancels (same map
// used for A and B => sum over k is permutation-invariant).
// LDS rows padded to 40 elems (80 B): 16B-aligned rows, 2-way banks (free).
// ---------------------------------------------------------------------------
#define LDKP 40
__global__ __launch_bounds__(256, 3)
void gemm_mfma_kernel(const float* __restrict__ A, const ushort* __restrict__ Wt_hi,
                      const ushort* __restrict__ Wt_lo, const float* __restrict__ bias,
                      float* __restrict__ Cout, int M, int N) {
    __shared__ ushort Ah[128][LDKP], Al[128][LDKP];
    __shared__ ushort Bh[64][LDKP], Bl[64][LDKP];

    const int tid = threadIdx.x;
    const int wave = tid >> 6;
    const int lane = tid & 63;
    const int fr = lane & 15;     // operand row (A: m, B: n) / D col
    const int fq = lane >> 4;     // k-octet / D row-quad
    const int m0 = blockIdx.x * 128;
    const int n0 = blockIdx.y * 64;

    f32x4 acc[2][4] = {};         // [mt][nt]

#pragma unroll 1
    for (int kt = 0; kt < 4; ++kt) {
        const int kb = kt * 32;
        // --- stage A tile 128x32 fp32 -> hi/lo bf16 planes ---
        // 1024 float4 / 256 thr = 4 each; 8 float4 per row.
#pragma unroll
        for (int i = 0; i < 4; ++i) {
            int f4 = tid + i * 256;
            int r = f4 >> 3, c4 = f4 & 7;
            float4 v = *reinterpret_cast<const float4*>(
                &A[(size_t)(m0 + r) * CC + kb + c4 * 4]);
            ushort h0 = bf16_rne(v.x), h1 = bf16_rne(v.y);
            ushort h2 = bf16_rne(v.z), h3 = bf16_rne(v.w);
            ushort l0 = bf16_rne(v.x - bf16_to_f(h0));
            ushort l1 = bf16_rne(v.y - bf16_to_f(h1));
            ushort l2 = bf16_rne(v.z - bf16_to_f(h2));
            ushort l3 = bf16_rne(v.w - bf16_to_f(h3));
            *reinterpret_cast<ushort4*>(&Ah[r][c4 * 4]) = make_ushort4(h0, h1, h2, h3);
            *reinterpret_cast<ushort4*>(&Al[r][c4 * 4]) = make_ushort4(l0, l1, l2, l3);
        }
        // --- stage B tile 64x32 from pre-split Wt planes (bf16, [N][128]) ---
        // 256 x 16B chunks per plane / 256 thr = 1 each.
        {
            int r = tid >> 2, c8 = tid & 3;
            *reinterpret_cast<uint4*>(&Bh[r][c8 * 8]) = *reinterpret_cast<const uint4*>(
                &Wt_hi[(size_t)(n0 + r) * CC + kb + c8 * 8]);
            *reinterpret_cast<uint4*>(&Bl[r][c8 * 8]) = *reinterpret_cast<const uint4*>(
                &Wt_lo[(size_t)(n0 + r) * CC + kb + c8 * 8]);
        }
        __syncthreads();

        // --- MFMA: K=32 per iter, kk = fq*8 covers it ---
        const int kk = fq * 8;
        bf16x8 bh[4], bl[4];
#pragma unroll
        for (int nt = 0; nt < 4; ++nt) {
            bh[nt] = *reinterpret_cast<const bf16x8*>(&Bh[nt * 16 + fr][kk]);
            bl[nt] = *reinterpret_cast<const bf16x8*>(&Bl[nt * 16 + fr][kk]);
        }
#pragma unroll
        for (int mt = 0; mt < 2; ++mt) {
            const int row = wave * 32 + mt * 16 + fr;
            bf16x8 ah = *reinterpret_cast<const bf16x8*>(&Ah[row][kk]);
            bf16x8 al = *reinterpret_cast<const bf16x8*>(&Al[row][kk]);
#pragma unroll
            for (int nt = 0; nt < 4; ++nt) {
                acc[mt][nt] = __builtin_amdgcn_mfma_f32_16x16x32_bf16(ah, bh[nt], acc[mt][nt], 0, 0, 0);
                acc[mt][nt] = __builtin_amdgcn_mfma_f32_16x16x32_bf16(ah, bl[nt], acc[mt][nt], 0, 0, 0);
                acc[mt][nt] = __builtin_amdgcn_mfma_f32_16x16x32_bf16(al, bh[nt], acc[mt][nt], 0, 0, 0);
            }
        }
        __syncthreads();
    }

    // --- epilogue: D frag -> C + bias. D: col=lane&15, row=(lane>>4)*4+reg ---
#pragma unroll
    for (int mt = 0; mt < 2; ++mt) {
#pragma unroll
        for (int nt = 0; nt < 4; ++nt) {
            const int n = n0 + nt * 16 + fr;
            const float bv = bias[n];
#pragma unroll
            for (int r = 0; r < 4; ++r) {
                const int m = m0 + wave * 32 + mt * 16 + fq * 4 + r;
                Cout[(size_t)m * N + n] = acc[mt][nt][r] + bv;
            }
        }
    }
}

// ---------------------------------------------------------------------------
// Windowed attention v2 (unchanged from round 14's passing run):
// 4 pixels per wave (16 lanes each), lane owns 8 channels, 2-shuffle reduce.
// qkv layout per pixel: [0:128)=Q, [128:256)=K, [256:384)=V.
// ---------------------------------------------------------------------------
__global__ __launch_bounds__(256)
void attn_kernel(const float* __restrict__ qkv, float* __restrict__ attn_out) {
    const int tid = threadIdx.x;
    const int sub = tid & 15;
    const int pix = blockIdx.x * 16 + (tid >> 4);
    const int c0 = sub * 8;

    const int bw = pix / (HH * WW);
    const int rem = pix - bw * (HH * WW);
    const int y = rem / WW;
    const int x = rem - y * WW;
    const float scale = 0.1767766952966369f;  // 1/sqrt(32)

    const float4 q0 = *reinterpret_cast<const float4*>(&qkv[(size_t)pix * 384 + c0]);
    const float4 q1 = *reinterpret_cast<const float4*>(&qkv[(size_t)pix * 384 + c0 + 4]);

    float s[WSZ];
    int np[WSZ];

#pragma unroll
    for (int dy = 0; dy < WS1; ++dy) {
        int yy = y + dy - RAD;
        yy = yy < 0 ? -yy : (yy >= HH ? 2 * (HH - 1) - yy : yy);
#pragma unroll
        for (int dx = 0; dx < WS1; ++dx) {
            int xx = x + dx - RAD;
            xx = xx < 0 ? -xx : (xx >= WW ? 2 * (WW - 1) - xx : xx);
            const int wi = dy * WS1 + dx;
            const int n = (bw * HH + yy) * WW + xx;
            np[wi] = n;
            const float4 k0 =
                *reinterpret_cast<const float4*>(&qkv[(size_t)n * 384 + 128 + c0]);
            const float4 k1 =
                *reinterpret_cast<const float4*>(&qkv[(size_t)n * 384 + 128 + c0 + 4]);
            float partial = q0.x * k0.x + q0.y * k0.y + q0.z * k0.z + q0.w * k0.w +
                            q1.x * k1.x + q1.y * k1.y + q1.z * k1.z + q1.w * k1.w;
            partial += __shfl_xor(partial, 1);
            partial += __shfl_xor(partial, 2);
            s[wi] = partial * scale;
        }
    }

    float mx = s[0];
#pragma unroll
    for (int i = 1; i < WSZ; ++i) mx = fmaxf(mx, s[i]);
    float sum = 0.f;
#pragma unroll
    for (int i = 0; i < WSZ; ++i) {
        s[i] = __expf(s[i] - mx);
        sum += s[i];
    }
    const float inv = 1.0f / sum;

    float4 o0 = make_float4(0.f, 0.f, 0.f, 0.f);
    float4 o1 = make_float4(0.f, 0.f, 0.f, 0.f);
#pragma unroll
    for (int i = 0; i < WSZ; ++i) {
        const float4 v0 =
            *reinterpret_cast<const float4*>(&qkv[(size_t)np[i] * 384 + 256 + c0]);
        const float4 v1 =
            *reinterpret_cast<const float4*>(&qkv[(size_t)np[i] * 384 + 256 + c0 + 4]);
        const float p = s[i] * inv;
        o0.x += p * v0.x; o0.y += p * v0.y; o0.z += p * v0.z; o0.w += p * v0.w;
        o1.x += p * v1.x; o1.y += p * v1.y; o1.z += p * v1.z; o1.w += p * v1.w;
    }

    *reinterpret_cast<float4*>(&attn_out[(size_t)pix * 128 + c0]) = o0;
    *reinterpret_cast<float4*>(&attn_out[(size_t)pix * 128 + c0 + 4]) = o1;
}

// ---------------------------------------------------------------------------
extern "C" void kernel_launch(void* const* d_in, const int* in_sizes, int n_in,
                              void* d_out, int out_size, void* d_ws, size_t ws_size,
                              hipStream_t stream) {
    const float* x = (const float*)d_in[0];       // [B,H,W,C]
    const float* w_qkv = (const float*)d_in[1];   // [C, 3C] row-major (in,out)
    const float* b_qkv = (const float*)d_in[2];   // [3C]
    const float* w_out = (const float*)d_in[3];   // [C, C]
    const float* b_out = (const float*)d_in[4];   // [C]
    float* out = (float*)d_out;

    // ws carve (all 16B-aligned): qkv 38.5MB | attn_out 12.8MB | Wt planes 256KB
    float* qkv = (float*)d_ws;
    float* attn_out = qkv + (size_t)M_TOT * 3 * CC;
    ushort* wq_hi = (ushort*)(attn_out + (size_t)M_TOT * CC);
    ushort* wq_lo = wq_hi + 384 * CC;
    ushort* wo_hi = wq_lo + 384 * CC;
    ushort* wo_lo = wo_hi + CC * CC;

    // Pre-pass: transpose + hi/lo-split both weight matrices.
    wsplit_kernel<<<(CC * 384) / 256, 256, 0, stream>>>(w_qkv, wq_hi, wq_lo, 384);
    wsplit_kernel<<<(CC * CC) / 256, 256, 0, stream>>>(w_out, wo_hi, wo_lo, CC);

    // Kernel A: qkv = x @ w_qkv + b_qkv   (M=25088, N=384, K=128), MFMA.
    gemm_mfma_kernel<<<dim3(M_TOT / 128, 384 / 64), 256, 0, stream>>>(
        x, wq_hi, wq_lo, b_qkv, qkv, M_TOT, 384);

    // Kernel B: windowed attention (4 pixels/wave).
    attn_kernel<<<M_TOT / 16, 256, 0, stream>>>(qkv, attn_out);

    // Kernel C: out = attn_out @ w_out + b_out   (N=128), MFMA.
    gemm_mfma_kernel<<<dim3(M_TOT / 128, CC / 64), 256, 0, stream>>>(
        attn_out, wo_hi, wo_lo, b_out, out, M_TOT, CC);
}